// Round 6
// baseline (81.705 us; speedup 1.0000x reference)
//
#include <hip/hip_runtime.h>

// CRPS loss: out = mean(|y_pred - y|) - sum_{i,k,l}|x[i,k]-x[i,l]| / (N*2*M^2)
// N=4096 rows, M=256 ensemble.
//
// R5 post-mortem: bitonic sorted-rank REGRESSED (65.3 -> 71.9us) — 21 serially
// dependent shuffle substages (DS-latency-bound) + 1024 same-address atomics.
// R6: back to the p=2-instr/pair brute force (R4), but HALVE the pair count by
// symmetry. Rotation mapping over 64 tiles of 4: for s=1..31 lane t handles
// tile-pair (t, t+s mod 64) — each unordered inter-tile pair once; s=32 sums
// both orders (counted once); intra-tile 6 pairs once.
//   mix_ordered = 2*(m_inter_1..31 + m_intra) + m_s32
// LDS: row stored TWICE (128 float4) so r4[lane+s] never wraps -> every read
// is ds_read_b128 with an immediate offset (no per-iter address VALU).
// Global combine: last-block-done (ws partials + counter + threadfence), one
// plain store to out — no same-address float atomics, no second kernel.
// VALU floor: ~1050 instr/wave * 2cy * 4 waves/SIMD = 8.4k cy = 3.5us.

constexpr int N_ROWS = 4096;
constexpr int M_COLS = 256;
constexpr int ROWS_PER_BLOCK = 4;                    // 4 waves x 1 row
constexpr int NUM_BLOCKS = N_ROWS / ROWS_PER_BLOCK;  // 1024

// m += |a - b| as exactly 2 VALU instrs (v_sub + v_add with |.| modifier).
__device__ __forceinline__ void abs_acc(float& m, float a, float b) {
    float t = a - b;
    asm("v_add_f32 %0, %0, |%1|" : "+v"(m) : "v"(t));
}

__global__ __launch_bounds__(256)
void crps_kernel(const float* __restrict__ y_pred,
                 const float* __restrict__ y,
                 float* __restrict__ ws_partial,
                 unsigned int* __restrict__ ws_count,
                 float* __restrict__ out) {
    __shared__ __align__(16) float4 rows[ROWS_PER_BLOCK][2 * M_COLS / 4];
    __shared__ float wsum[ROWS_PER_BLOCK];
    __shared__ bool is_last;

    const int wave = threadIdx.x >> 6;               // 0..3 -> row of block
    const int lane = threadIdx.x & 63;
    const int row  = blockIdx.x * ROWS_PER_BLOCK + wave;

    // Lane owns tile t=lane: elements 4t..4t+3. Stage row twice in LDS so the
    // rotated reads below never need a mod-64 wrap.
    const float4 xk = reinterpret_cast<const float4*>(y_pred + row * M_COLS)[lane];
    rows[wave][lane]      = xk;
    rows[wave][lane + 64] = xk;
    const float yi = y[row];                         // wave-uniform

    const float xo[4] = {xk.x, xk.y, xk.z, xk.w};

    // MAE term.
    float mae = 0.0f;
    #pragma unroll
    for (int j = 0; j < 4; ++j) abs_acc(mae, xo[j], yi);

    // Intra-tile unordered pairs (6).
    float m = 0.0f, m32 = 0.0f;
    abs_acc(m, xo[0], xo[1]); abs_acc(m, xo[0], xo[2]); abs_acc(m, xo[0], xo[3]);
    abs_acc(m, xo[1], xo[2]); abs_acc(m, xo[1], xo[3]); abs_acc(m, xo[2], xo[3]);

    // Inter-tile: s = 1..31 (each unordered pair once), s = 32 (both orders).
    // No barrier: this wave reads only its own row (same-wave DS ordering).
    const float4* r4 = &rows[wave][lane];            // r4[s], imm offset 16*s
    #pragma unroll
    for (int s = 1; s <= 31; ++s) {
        const float4 v = r4[s];
        #pragma unroll
        for (int j = 0; j < 4; ++j) {
            abs_acc(m, xo[j], v.x); abs_acc(m, xo[j], v.y);
            abs_acc(m, xo[j], v.z); abs_acc(m, xo[j], v.w);
        }
    }
    {
        const float4 v = r4[32];
        #pragma unroll
        for (int j = 0; j < 4; ++j) {
            abs_acc(m32, xo[j], v.x); abs_acc(m32, xo[j], v.y);
            abs_acc(m32, xo[j], v.z); abs_acc(m32, xo[j], v.w);
        }
    }

    // mix_loss contribution = (2*m + m32) / (2*N*M^2) = (m + 0.5*m32)/(N*M^2)
    constexpr float mae_scale = 1.0f / ((float)N_ROWS * (float)M_COLS);       // 2^-20
    constexpr float inv_NM2   = 1.0f / ((float)N_ROWS * (float)M_COLS * (float)M_COLS); // 2^-28
    float part = mae * mae_scale - (m + 0.5f * m32) * inv_NM2;

    // Wave reduction, then block partial.
    #pragma unroll
    for (int off = 32; off > 0; off >>= 1)
        part += __shfl_down(part, off, 64);

    if (lane == 0) wsum[wave] = part;
    __syncthreads();
    if (threadIdx.x == 0) {
        ws_partial[blockIdx.x] = (wsum[0] + wsum[1]) + (wsum[2] + wsum[3]);
        __threadfence();                             // release partial
        const unsigned int prev = atomicAdd(ws_count, 1u);
        is_last = (prev == NUM_BLOCKS - 1);
    }
    __syncthreads();

    // Last finished block reduces the 1024 partials and stores the scalar.
    if (is_last) {
        __threadfence();                             // acquire partials
        const float4 p4 = reinterpret_cast<const float4*>(ws_partial)[threadIdx.x];
        float v = (p4.x + p4.y) + (p4.z + p4.w);
        #pragma unroll
        for (int off = 32; off > 0; off >>= 1)
            v += __shfl_down(v, off, 64);
        if (lane == 0) wsum[wave] = v;
        __syncthreads();
        if (threadIdx.x == 0)
            *out = (wsum[0] + wsum[1]) + (wsum[2] + wsum[3]);
    }
}

extern "C" void kernel_launch(void* const* d_in, const int* in_sizes, int n_in,
                              void* d_out, int out_size, void* d_ws, size_t ws_size,
                              hipStream_t stream) {
    const float* y_pred = (const float*)d_in[0];
    const float* y      = (const float*)d_in[1];
    float* out          = (float*)d_out;
    float* ws_partial   = (float*)d_ws;                       // 1024 floats
    unsigned int* ws_count = (unsigned int*)((char*)d_ws + NUM_BLOCKS * sizeof(float));

    // ws is re-poisoned to 0xAA before each timed launch: zero the counter.
    hipMemsetAsync(ws_count, 0, sizeof(unsigned int), stream);

    crps_kernel<<<NUM_BLOCKS, 256, 0, stream>>>(y_pred, y, ws_partial, ws_count, out);
}

// Round 8
// 62.603 us; speedup vs baseline: 1.3051x; 1.3051x over previous
//
#include <hip/hip_runtime.h>

// CRPS loss: out = mean(|y_pred - y|) - sum_{i,k,l}|x[i,k]-x[i,l]| / (N*2*M^2)
// N=4096 rows, M=256 ensemble.
//
// R7 post-mortem: absmax 0.121 = 7/31.5 of the mix term -> the 7 REMAINDER
// iterations of `#pragma unroll 8` over the 31-iter s-loop were miscompiled
// (partial-unroll epilogue x "+v" inline-asm accumulator). The rotation math
// itself is proven (R6 passed, fully unrolled). R8 = same compute, remainder-
// free loop structure:
//   s=1..24  : #pragma unroll 8 (3 exact chunks, <=8 loads in flight)
//   s=25..31 : full unroll (straight-line)
//   s=32     : inline, weight 0.5 (both orders counted)
// Combine: R4's proven two-kernel scheme (block partials -> ws, kernel2
// reduces 1024 floats, plain store). No atomics, no fences, no memset.
//
// Pair accounting (64 tiles of 4 elems, lane t owns tile t):
//   s=1..31: tile-pair (t, t+s mod 64) -> each unordered inter-tile pair once
//   s=32:    each d=32 pair appears in both orders -> weight 0.5
//   intra-tile: 6 pairs, once
//   mix_ordered = 2*(m_intra + m_inter) + m32

constexpr int N_ROWS = 4096;
constexpr int M_COLS = 256;
constexpr int ROWS_PER_BLOCK = 4;                    // 4 waves x 1 row
constexpr int NUM_BLOCKS = N_ROWS / ROWS_PER_BLOCK;  // 1024

// m += |a - b| as exactly 2 VALU instrs (v_sub + v_add with |.| modifier).
__device__ __forceinline__ void abs_acc(float& m, float a, float b) {
    float t = a - b;
    asm("v_add_f32 %0, %0, |%1|" : "+v"(m) : "v"(t));
}

__global__ __launch_bounds__(256)
void crps_partial(const float* __restrict__ y_pred,
                  const float* __restrict__ y,
                  float* __restrict__ partial) {
    __shared__ __align__(16) float4 rows[ROWS_PER_BLOCK][2 * M_COLS / 4];
    __shared__ float wsum[ROWS_PER_BLOCK];

    const int wave = threadIdx.x >> 6;               // 0..3 -> row of block
    const int lane = threadIdx.x & 63;
    const int row  = blockIdx.x * ROWS_PER_BLOCK + wave;

    // Lane owns tile t=lane (elements 4t..4t+3); stage row twice so rotated
    // reads r4[lane+s] never wrap mod 64.
    const float4 xk = reinterpret_cast<const float4*>(y_pred + row * M_COLS)[lane];
    rows[wave][lane]      = xk;
    rows[wave][lane + 64] = xk;
    const float yi = y[row];                         // wave-uniform

    const float xo[4] = {xk.x, xk.y, xk.z, xk.w};

    // MAE term.
    float mae = 0.0f;
    #pragma unroll
    for (int j = 0; j < 4; ++j) abs_acc(mae, xo[j], yi);

    // 4 independent accumulator chains; intra-tile pairs spread across them.
    float m[4] = {0.0f, 0.0f, 0.0f, 0.0f};
    abs_acc(m[0], xo[0], xo[1]); abs_acc(m[1], xo[0], xo[2]);
    abs_acc(m[2], xo[0], xo[3]); abs_acc(m[3], xo[1], xo[2]);
    abs_acc(m[0], xo[1], xo[3]); abs_acc(m[1], xo[2], xo[3]);

    // No barrier needed: wave reads only LDS it wrote itself (same-wave DS
    // ordering) — pattern proven in R3/R4/R6.
    const float4* r4 = &rows[wave][lane];            // r4[s] -> imm offset 16s

    // s = 1..24: exactly 3 chunks of 8 — NO remainder epilogue.
    #pragma unroll 8
    for (int s = 1; s <= 24; ++s) {
        const float4 v = r4[s];
        #pragma unroll
        for (int j = 0; j < 4; ++j) {
            abs_acc(m[j], xo[j], v.x); abs_acc(m[j], xo[j], v.y);
            abs_acc(m[j], xo[j], v.z); abs_acc(m[j], xo[j], v.w);
        }
    }
    // s = 25..31: straight-line full unroll — NO remainder epilogue.
    #pragma unroll
    for (int s = 25; s <= 31; ++s) {
        const float4 v = r4[s];
        #pragma unroll
        for (int j = 0; j < 4; ++j) {
            abs_acc(m[j], xo[j], v.x); abs_acc(m[j], xo[j], v.y);
            abs_acc(m[j], xo[j], v.z); abs_acc(m[j], xo[j], v.w);
        }
    }
    // s = 32: every pair counted in both orders across the wave -> weight 0.5.
    float m32 = 0.0f;
    {
        const float4 v = r4[32];
        #pragma unroll
        for (int j = 0; j < 4; ++j) {
            abs_acc(m32, xo[j], v.x); abs_acc(m32, xo[j], v.y);
            abs_acc(m32, xo[j], v.z); abs_acc(m32, xo[j], v.w);
        }
    }

    const float msum = (m[0] + m[1]) + (m[2] + m[3]);

    // mix contribution = (2*msum + m32)/(2*N*M^2) = (msum + 0.5*m32)/(N*M^2)
    constexpr float mae_scale = 1.0f / ((float)N_ROWS * (float)M_COLS);
    constexpr float inv_NM2   = 1.0f / ((float)N_ROWS * (float)M_COLS * (float)M_COLS);
    float part = mae * mae_scale - (msum + 0.5f * m32) * inv_NM2;

    // Wave reduction -> block partial (no atomics, no fences).
    #pragma unroll
    for (int off = 32; off > 0; off >>= 1)
        part += __shfl_down(part, off, 64);

    if (lane == 0) wsum[wave] = part;
    __syncthreads();
    if (threadIdx.x == 0)
        partial[blockIdx.x] = (wsum[0] + wsum[1]) + (wsum[2] + wsum[3]);
}

__global__ __launch_bounds__(256)
void crps_final(const float* __restrict__ partial, float* __restrict__ out) {
    __shared__ float wsum[4];
    const int t = threadIdx.x;
    const float4 v4 = reinterpret_cast<const float4*>(partial)[t];
    float v = (v4.x + v4.y) + (v4.z + v4.w);
    #pragma unroll
    for (int off = 32; off > 0; off >>= 1)
        v += __shfl_down(v, off, 64);
    if ((t & 63) == 0) wsum[t >> 6] = v;
    __syncthreads();
    if (t == 0)
        *out = (wsum[0] + wsum[1]) + (wsum[2] + wsum[3]);
}

extern "C" void kernel_launch(void* const* d_in, const int* in_sizes, int n_in,
                              void* d_out, int out_size, void* d_ws, size_t ws_size,
                              hipStream_t stream) {
    const float* y_pred = (const float*)d_in[0];
    const float* y      = (const float*)d_in[1];
    float* out          = (float*)d_out;
    float* ws           = (float*)d_ws;              // 1024 floats used

    crps_partial<<<NUM_BLOCKS, 256, 0, stream>>>(y_pred, y, ws);
    crps_final<<<1, 256, 0, stream>>>(ws, out);
}